// Round 16
// baseline (305.245 us; speedup 1.0000x reference)
//
#include <hip/hip_runtime.h>
#include <hip/hip_bf16.h>

#define CC 728
#define PP 364          // pairs (even/odd phase length)
#define KP 384          // padded pair-K
#define KT 12
#define ROWS 32         // rows per block
#define NWG 1444        // 46208 / 32

typedef __attribute__((ext_vector_type(8))) short bf16x8;
typedef __attribute__((ext_vector_type(8))) unsigned short ushort8;
typedef __attribute__((ext_vector_type(4))) float f32x4;

// round-to-nearest-even fp32 -> bf16 bits
__device__ __forceinline__ unsigned int f2bf(float f) {
    unsigned int u = __float_as_uint(f);
    unsigned int r = u + 0x7fffu + ((u >> 16) & 1u);
    return r >> 16;
}

__device__ __forceinline__ float bf2f(unsigned short v) {
    unsigned int u = ((unsigned int)v) << 16;
    return __uint_as_float(u);
}

__device__ __forceinline__ void gload_lds16(const void* g, void* l) {
    __builtin_amdgcn_global_load_lds(
        (const __attribute__((address_space(1))) void*)g,
        (__attribute__((address_space(3))) void*)l,
        16, 0, 0);
}

// h[d] for odd d (validated closed form, rounds 1-15):
//   h[d] = s * cos(pi d/728) / (728 sin(pi d/728)),  s = +1 if (d>>1)&1 else -1
// Bt1[n][k] = h[2*((n-k-1) mod 364)+1]   (Ye = 0.5 E + Bt1 . O)
// Bt2[n][k] = h[2*((n-k)   mod 364)+1]   (Yo = 0.5 O + Bt2 . E)
// Both padded to [384][384] bf16, zero outside n<364 && k<364.
__global__ void build_bt(unsigned short* __restrict__ bt1,
                         unsigned short* __restrict__ bt2) {
    int idx = blockIdx.x * blockDim.x + threadIdx.x;
    if (idx >= 2 * KP * KP) return;
    int mat = idx / (KP * KP);
    int rem = idx % (KP * KP);
    int n = rem / KP, k = rem % KP;
    float v = 0.f;
    if (n < PP && k < PP) {
        int m = n - k - (mat == 0 ? 1 : 0);
        if (m < 0) m += PP;
        int d = 2 * m + 1;
        float t = (float)(3.14159265358979323846 * (double)d / (double)CC);
        float s = ((d >> 1) & 1) ? 1.f : -1.f;
        v = s * cosf(t) / ((float)CC * sinf(t));
    }
    (mat == 0 ? bt1 : bt2)[n * KP + k] = (unsigned short)f2bf(v);
}

// Fused convert + split GEMM, A-resident + DMA-staged B:
//  Phase 1: block converts its OWN 32x728 fp32 rows -> E/O bf16 in LDS
//           (transposed [kc][row^sw] chunk layout). x read ONCE.
//  K-loop:  B tiles ([lhi][n] transposed chunks, linear DMA dest) double-
//           buffered via global_load_lds; counted vmcnt(6) + raw s_barriers
//           keep B(t+1) in flight across the whole step. A via conflict-free
//           ds_read from the resident panel. No full vmcnt drains.
//  Epilogue: 0.5*identity from LDS, relu, guarded float2 stores.
//   out[r][2n]   = relu(0.5 E[r][n] + sum_k Bt1[n][k] * O[r][k])
//   out[r][2n+1] = relu(0.5 O[r][n] + sum_k Bt2[n][k] * E[r][k])
__global__ __launch_bounds__(512, 2) void fused_gemm_relu(
        const float* __restrict__ x,
        const unsigned short* __restrict__ bt1,
        const unsigned short* __restrict__ bt2,
        float* __restrict__ out) {
    __shared__ unsigned short ldsE[48 * 32 * 8];      // 24 KB [kc][row^sw]
    __shared__ unsigned short ldsO[48 * 32 * 8];      // 24 KB
    __shared__ unsigned short ldsB1[2][1536 * 8];     // 2 x 24 KB [lhi][n]
    __shared__ unsigned short ldsB2[2][1536 * 8];     // 2 x 24 KB  => 144 KB

    const int tid  = threadIdx.x;
    const int lane = tid & 63;
    const int wid  = tid >> 6;                        // 0..7: n-strip
    const int l15  = lane & 15, lhi = lane >> 4;      // lhi 0..3
    const int bm   = blockIdx.x * ROWS;
    const int nb   = wid * 48;                        // wave's pair-col base

    // ---- B staging: transposed chunk layout, dest EXACTLY linear in c ----
    auto stageB = [&](int buf, int kt) {              // 6 DMA / thread
        int k0 = kt * 32;
#pragma unroll
        for (int i = 0; i < 3; ++i) {
            int c  = i * 512 + tid;                   // 0..1535
            int lc = c / 384, n = c % 384;            // wave-uniform lc
            size_t so = (size_t)n * KP + k0 + lc * 8;
            gload_lds16(bt1 + so, &ldsB1[buf][c * 8]);
            gload_lds16(bt2 + so, &ldsB2[buf][c * 8]);
        }
    };

    // ---- prologue: B(0) DMA first, convert overlaps its flight ----
    stageB(0, 0);
#pragma unroll
    for (int i = 0; i < 3; ++i) {
        int idx = i * 512 + tid;                      // 32 rows * 48 chunks
        int row = idx / 48, p8 = idx % 48;
        int c0  = p8 * 16;                            // channel base
        ushort8 ve, vo;
#pragma unroll
        for (int j = 0; j < 8; ++j) { ve[j] = 0; vo[j] = 0; }
        const float4* src = (const float4*)(x + (size_t)(bm + row) * CC + c0);
#pragma unroll
        for (int j = 0; j < 4; ++j) {
            if (c0 + 4 * j < CC) {
                float4 f = src[j];
                ve[2 * j]     = (unsigned short)f2bf(f.x);
                vo[2 * j]     = (unsigned short)f2bf(f.y);
                ve[2 * j + 1] = (unsigned short)f2bf(f.z);
                vo[2 * j + 1] = (unsigned short)f2bf(f.w);
            }
        }
        int rsw = row ^ ((p8 & 15) << 1);             // bijective row swizzle
        *(ushort8*)&ldsE[(p8 * 32 + rsw) * 8] = ve;
        *(ushort8*)&ldsO[(p8 * 32 + rsw) * 8] = vo;
    }
    __syncthreads();          // drains B(0) DMA + x loads + E/O writes
    stageB(1, 1);             // flies during compute(0)

    f32x4 acc_e[2][3], acc_o[2][3];
#pragma unroll
    for (int i = 0; i < 2; ++i)
#pragma unroll
        for (int j = 0; j < 3; ++j)
#pragma unroll
            for (int rr = 0; rr < 4; ++rr) { acc_e[i][j][rr] = 0.f; acc_o[i][j][rr] = 0.f; }

    auto compute = [&](int buf, int kt) {
        bf16x8 aE[2], aO[2], b1[3], b2[3];
        const int kc = kt * 4 + lhi;
#pragma unroll
        for (int mi = 0; mi < 2; ++mi) {
            int rsw = (mi * 16 + l15) ^ ((kc & 15) << 1);
            aE[mi] = *(const bf16x8*)&ldsE[(kc * 32 + rsw) * 8];
            aO[mi] = *(const bf16x8*)&ldsO[(kc * 32 + rsw) * 8];
        }
#pragma unroll
        for (int nf = 0; nf < 3; ++nf) {
            int n = nb + nf * 16 + l15;
            b1[nf] = *(const bf16x8*)&ldsB1[buf][(lhi * 384 + n) * 8];
            b2[nf] = *(const bf16x8*)&ldsB2[buf][(lhi * 384 + n) * 8];
        }
        __builtin_amdgcn_s_setprio(1);
#pragma unroll
        for (int mi = 0; mi < 2; ++mi)
#pragma unroll
            for (int nf = 0; nf < 3; ++nf) {
                acc_e[mi][nf] = __builtin_amdgcn_mfma_f32_16x16x32_bf16(
                    aO[mi], b1[nf], acc_e[mi][nf], 0, 0, 0);
                acc_o[mi][nf] = __builtin_amdgcn_mfma_f32_16x16x32_bf16(
                    aE[mi], b2[nf], acc_o[mi][nf], 0, 0, 0);
            }
        __builtin_amdgcn_s_setprio(0);
    };

    // ---- K-loop: counted vmcnt, raw barriers, B(t+1) always in flight ----
    compute(0, 0);                        // B(0) drained by __syncthreads
    __builtin_amdgcn_s_barrier();         // readers done with buf0
    __builtin_amdgcn_sched_barrier(0);
    stageB(0, 2);                         // refill buf0 with B(2)

#pragma unroll
    for (int t = 1; t < KT; ++t) {
        if (t + 1 < KT) asm volatile("s_waitcnt vmcnt(6)" ::: "memory"); // B(t) landed
        else            asm volatile("s_waitcnt vmcnt(0)" ::: "memory");
        __builtin_amdgcn_sched_barrier(0);
        __builtin_amdgcn_s_barrier();     // all waves' B(t) visible
        compute(t & 1, t);
        __builtin_amdgcn_s_barrier();     // readers done with buf t&1
        __builtin_amdgcn_sched_barrier(0);
        if (t + 2 < KT) stageB(t & 1, t + 2);
    }

    // ---- epilogue: +0.5*E/O from LDS, relu, guarded float2 stores ----
#pragma unroll
    for (int mi = 0; mi < 2; ++mi) {
#pragma unroll
        for (int nf = 0; nf < 3; ++nf) {
            int colp = nb + nf * 16 + l15;
            if (colp < PP) {
                int kc = colp >> 3, el = colp & 7;
#pragma unroll
                for (int rr = 0; rr < 4; ++rr) {
                    int row = mi * 16 + lhi * 4 + rr;
                    int rsw = row ^ ((kc & 15) << 1);
                    float fe = bf2f(ldsE[(kc * 32 + rsw) * 8 + el]);
                    float fo = bf2f(ldsO[(kc * 32 + rsw) * 8 + el]);
                    float ye = 0.5f * fe + acc_e[mi][nf][rr];
                    float yo = 0.5f * fo + acc_o[mi][nf][rr];
                    float2 ov;
                    ov.x = ye > 0.f ? ye : 0.f;
                    ov.y = yo > 0.f ? yo : 0.f;
                    *(float2*)&out[(size_t)(bm + row) * CC + 2 * colp] = ov;
                }
            }
        }
    }
}

extern "C" void kernel_launch(void* const* d_in, const int* in_sizes, int n_in,
                              void* d_out, int out_size, void* d_ws, size_t ws_size,
                              hipStream_t stream) {
    const float* x = (const float*)d_in[0];
    float* out = (float*)d_out;

    unsigned short* bt1 = (unsigned short*)d_ws;            // 384*384 bf16
    unsigned short* bt2 = bt1 + KP * KP;                    // 384*384 bf16

    build_bt<<<(2 * KP * KP + 255) / 256, 256, 0, stream>>>(bt1, bt2);
    fused_gemm_relu<<<NWG, 512, 0, stream>>>(x, bt1, bt2, out);
}

// Round 17
// 153.797 us; speedup vs baseline: 1.9847x; 1.9847x over previous
//
#include <hip/hip_runtime.h>
#include <hip/hip_bf16.h>

#define CC 728
#define PP 364          // pairs (even/odd phase length)
#define KP 384          // padded pair-K: 12 * 32
#define KT 12
#define M_ROWS 46208    // 32*38*38 = 361 * 128
#define NWG 1083        // 361 m-tiles * 3 n-tiles (128 pairs each)

typedef __attribute__((ext_vector_type(8))) short bf16x8;
typedef __attribute__((ext_vector_type(8))) unsigned short ushort8;
typedef __attribute__((ext_vector_type(4))) float f32x4;

// round-to-nearest-even fp32 -> bf16 bits
__device__ __forceinline__ unsigned int f2bf(float f) {
    unsigned int u = __float_as_uint(f);
    unsigned int r = u + 0x7fffu + ((u >> 16) & 1u);
    return r >> 16;
}

__device__ __forceinline__ float bf2f(unsigned short v) {
    unsigned int u = ((unsigned int)v) << 16;
    return __uint_as_float(u);
}

__device__ __forceinline__ void gload_lds16(const void* g, void* l) {
    __builtin_amdgcn_global_load_lds(
        (const __attribute__((address_space(1))) void*)g,
        (__attribute__((address_space(3))) void*)l,
        16, 0, 0);
}

// h[d] for odd d (validated closed form, rounds 1-16):
//   h[d] = s * cos(pi d/728) / (728 sin(pi d/728)),  s = +1 if (d>>1)&1 else -1
// Bt1[n][k] = h[2*((n-k-1) mod 364)+1]   (Ye = 0.5 E + Bt1 . O)
// Bt2[n][k] = h[2*((n-k)   mod 364)+1]   (Yo = 0.5 O + Bt2 . E)
// Both padded to [384][384] bf16, zero outside n<364 && k<364.
__global__ void build_bt(unsigned short* __restrict__ bt1,
                         unsigned short* __restrict__ bt2) {
    int idx = blockIdx.x * blockDim.x + threadIdx.x;
    if (idx >= 2 * KP * KP) return;
    int mat = idx / (KP * KP);
    int rem = idx % (KP * KP);
    int n = rem / KP, k = rem % KP;
    float v = 0.f;
    if (n < PP && k < PP) {
        int m = n - k - (mat == 0 ? 1 : 0);
        if (m < 0) m += PP;
        int d = 2 * m + 1;
        float t = (float)(3.14159265358979323846 * (double)d / (double)CC);
        float s = ((d >> 1) & 1) ? 1.f : -1.f;
        v = s * cosf(t) / ((float)CC * sinf(t));
    }
    (mat == 0 ? bt1 : bt2)[n * KP + k] = (unsigned short)f2bf(v);
}

// Pass 1: x fp32 [46208][728] -> e,o bf16 [46208][384] (de-interleaved, padded)
__global__ void convert_deint(const float* __restrict__ x,
                              unsigned short* __restrict__ e,
                              unsigned short* __restrict__ o) {
    int id = blockIdx.x * blockDim.x + threadIdx.x;   // r*48 + p8
    if (id >= M_ROWS * 48) return;
    int r  = id / 48, p8 = id % 48;
    int c0 = p8 * 16;
    ushort8 ve, vo;
#pragma unroll
    for (int j = 0; j < 8; ++j) { ve[j] = 0; vo[j] = 0; }
    if (c0 < CC) {
        const float4* src = (const float4*)(x + (size_t)r * CC + c0);
#pragma unroll
        for (int j = 0; j < 4; ++j) {
            float4 f = (c0 + 4 * j < CC) ? src[j] : make_float4(0.f, 0.f, 0.f, 0.f);
            ve[2 * j]     = (unsigned short)f2bf(f.x);
            vo[2 * j]     = (unsigned short)f2bf(f.y);
            ve[2 * j + 1] = (unsigned short)f2bf(f.z);
            vo[2 * j + 1] = (unsigned short)f2bf(f.w);
        }
    }
    *(ushort8*)(e + (size_t)r * KP + p8 * 8) = ve;
    *(ushort8*)(o + (size_t)r * KP + p8 * 8) = vo;
}

// Pass 2: split GEMM, R10's proven pure-DMA staging + 2-barrier schedule,
// DOUBLED tile: 128 rows x 128 pair-cols per block (R3 geometry, clean path).
// Halves per-output barrier/DMA-issue/step costs; LDS traffic per output x0.67.
//   out[r][2n]   = relu(0.5 E[r][n] + sum_k Bt1[n][k] * O[r][k])
//   out[r][2n+1] = relu(0.5 O[r][n] + sum_k Bt2[n][k] * E[r][k])
__global__ __launch_bounds__(256) void gemm_relu(
        const unsigned short* __restrict__ e,
        const unsigned short* __restrict__ o,
        const unsigned short* __restrict__ bt1,
        const unsigned short* __restrict__ bt2,
        float* __restrict__ out) {
    __shared__ unsigned short ldsE[128 * 32];    // 8 KB
    __shared__ unsigned short ldsO[128 * 32];    // 8 KB
    __shared__ unsigned short ldsB1[128 * 32];   // 8 KB
    __shared__ unsigned short ldsB2[128 * 32];   // 8 KB  => 32 KB

    const int tid  = threadIdx.x;
    const int lane = tid & 63;
    const int wid  = tid >> 6;
    const int wr   = wid >> 1, wc = wid & 1;     // 2x2 wave grid
    const int l15  = lane & 15, lhi = lane >> 4;

    // bijective XCD swizzle (m204); 3 consecutive wgids share an A row-panel
    const int NX = 8;
    int orig = blockIdx.x;
    int q = NWG / NX, r = NWG % NX;              // 135, 3
    int xcd = orig % NX, local = orig / NX;
    int wgid = (xcd < r ? xcd * (q + 1) : r * (q + 1) + (xcd - r) * q) + local;
    const int bm  = (wgid / 3) * 128;
    const int bnp = (wgid % 3) * 128;            // pair-col base

    f32x4 acc_e[4][4], acc_o[4][4];
#pragma unroll
    for (int i = 0; i < 4; ++i)
#pragma unroll
        for (int j = 0; j < 4; ++j)
#pragma unroll
            for (int rr = 0; rr < 4; ++rr) { acc_e[i][j][rr] = 0.f; acc_o[i][j][rr] = 0.f; }

    const int rowA = tid >> 2;     // 0..63 staging row base
    const int cq   = tid & 3;      // 16B chunk id

    for (int kt = 0; kt < KT; ++kt) {
        const int k0 = kt * 32;

        // ---- stage E,O,B1,B2 [128][32] each: 8 DMA / thread, swizzled src ----
#pragma unroll
        for (int i = 0; i < 2; ++i) {
            int row  = i * 64 + rowA;
            int gsrc = (cq - (row >> 1)) & 3;
            size_t soA = (size_t)(bm + row) * KP + k0 + gsrc * 8;
            size_t soB = (size_t)(bnp + row) * KP + k0 + gsrc * 8;
            gload_lds16(e   + soA, &ldsE[(i * 256 + tid) * 8]);
            gload_lds16(o   + soA, &ldsO[(i * 256 + tid) * 8]);
            gload_lds16(bt1 + soB, &ldsB1[(i * 256 + tid) * 8]);
            gload_lds16(bt2 + soB, &ldsB2[(i * 256 + tid) * 8]);
        }
        __syncthreads();   // drains DMA before reads

        // ---- frags + MFMA (32 per wave) ----
        bf16x8 aE[4], aO[4], b1[4], b2[4];
#pragma unroll
        for (int mi = 0; mi < 4; ++mi) {
            int row = wr * 64 + mi * 16 + l15;
            int c   = (lhi + (row >> 1)) & 3;
            aE[mi] = *(const bf16x8*)&ldsE[row * 32 + c * 8];
            aO[mi] = *(const bf16x8*)&ldsO[row * 32 + c * 8];
        }
#pragma unroll
        for (int nf = 0; nf < 4; ++nf) {
            int row = wc * 64 + nf * 16 + l15;
            int c   = (lhi + (row >> 1)) & 3;
            b1[nf] = *(const bf16x8*)&ldsB1[row * 32 + c * 8];
            b2[nf] = *(const bf16x8*)&ldsB2[row * 32 + c * 8];
        }
        __builtin_amdgcn_s_setprio(1);
#pragma unroll
        for (int mi = 0; mi < 4; ++mi)
#pragma unroll
            for (int nf = 0; nf < 4; ++nf) {
                acc_e[mi][nf] = __builtin_amdgcn_mfma_f32_16x16x32_bf16(
                    aO[mi], b1[nf], acc_e[mi][nf], 0, 0, 0);
                acc_o[mi][nf] = __builtin_amdgcn_mfma_f32_16x16x32_bf16(
                    aE[mi], b2[nf], acc_o[mi][nf], 0, 0, 0);
            }
        __builtin_amdgcn_s_setprio(0);
        __syncthreads();   // protect single-buffered LDS
    }

    // ---- epilogue: +0.5*E/O identity (L3-hot re-read), relu, float2 store ----
#pragma unroll
    for (int mi = 0; mi < 4; ++mi) {
#pragma unroll
        for (int nf = 0; nf < 4; ++nf) {
            int colp = bnp + wc * 64 + nf * 16 + l15;
            if (colp < PP) {
#pragma unroll
                for (int rr = 0; rr < 4; ++rr) {
                    int rowg = bm + wr * 64 + mi * 16 + lhi * 4 + rr;
                    size_t ib = (size_t)rowg * KP + colp;
                    float fe = bf2f(e[ib]);
                    float fo = bf2f(o[ib]);
                    float ye = 0.5f * fe + acc_e[mi][nf][rr];
                    float yo = 0.5f * fo + acc_o[mi][nf][rr];
                    float2 ov;
                    ov.x = ye > 0.f ? ye : 0.f;
                    ov.y = yo > 0.f ? yo : 0.f;
                    *(float2*)&out[(size_t)rowg * CC + 2 * colp] = ov;
                }
            }
        }
    }
}

extern "C" void kernel_launch(void* const* d_in, const int* in_sizes, int n_in,
                              void* d_out, int out_size, void* d_ws, size_t ws_size,
                              hipStream_t stream) {
    const float* x = (const float*)d_in[0];
    float* out = (float*)d_out;

    unsigned short* bt1 = (unsigned short*)d_ws;            // 384*384 bf16
    unsigned short* bt2 = bt1 + KP * KP;
    unsigned short* e   = bt2 + KP * KP;                    // 46208*384 bf16
    unsigned short* o   = e + (size_t)M_ROWS * KP;

    build_bt<<<(2 * KP * KP + 255) / 256, 256, 0, stream>>>(bt1, bt2);
    convert_deint<<<(M_ROWS * 48) / 256, 256, 0, stream>>>(x, e, o);
    gemm_relu<<<NWG, 256, 0, stream>>>(e, o, bt1, bt2, out);
}

// Round 18
// 130.778 us; speedup vs baseline: 2.3341x; 1.1760x over previous
//
#include <hip/hip_runtime.h>
#include <hip/hip_bf16.h>

#define CC 728
#define PP 364          // pairs (even/odd phase length)
#define KP 384          // padded pair-K
#define KT 12           // 11 full tiles + 1 overlapped tail tile (base 332)
#define M_ROWS 46208    // 32*38*38 = 361 * 128
#define NWG 2166        // 361 m-tiles * 6 n-tiles (64 pairs each)

typedef __attribute__((ext_vector_type(8))) short bf16x8;
typedef __attribute__((ext_vector_type(4))) float f32x4;

// round-to-nearest-even fp32 -> bf16 bits
__device__ __forceinline__ unsigned int f2bf(float f) {
    unsigned int u = __float_as_uint(f);
    unsigned int r = u + 0x7fffu + ((u >> 16) & 1u);
    return r >> 16;
}

__device__ __forceinline__ void gload_lds16(const void* g, void* l) {
    __builtin_amdgcn_global_load_lds(
        (const __attribute__((address_space(1))) void*)g,
        (__attribute__((address_space(3))) void*)l,
        16, 0, 0);
}

// h[d] for odd d (validated closed form, rounds 1-17):
//   h[d] = s * cos(pi d/728) / (728 sin(pi d/728)),  s = +1 if (d>>1)&1 else -1
// Bt1[n][k] = h[2*((n-k-1) mod 364)+1]   (Ye = 0.5 E + Bt1 . O)
// Bt2[n][k] = h[2*((n-k)   mod 364)+1]   (Yo = 0.5 O + Bt2 . E)
// btl1/btl2: tail tables [384 n][32 k] for the overlapped last tile at pair
// base 332 — k-rows 0..19 (pairs 332..351, already counted by tile 10) ZEROED,
// rows 20..31 = pairs 352..363.
__global__ void build_bt(unsigned short* __restrict__ bt1,
                         unsigned short* __restrict__ bt2,
                         unsigned short* __restrict__ btl1,
                         unsigned short* __restrict__ btl2) {
    int idx = blockIdx.x * blockDim.x + threadIdx.x;
    if (idx >= 2 * KP * KP + 2 * KP * 32) return;
    int n, k, mat;
    unsigned short* dst;
    bool valid;
    if (idx < 2 * KP * KP) {
        mat = idx / (KP * KP);
        int rem = idx % (KP * KP);
        n = rem / KP; k = rem % KP;
        dst = (mat == 0 ? bt1 : bt2) + n * KP + k;
        valid = (n < PP && k < PP);
    } else {
        int i2 = idx - 2 * KP * KP;
        mat = i2 / (KP * 32);
        int rem = i2 % (KP * 32);
        n = rem / 32; k = rem % 32;
        dst = (mat == 0 ? btl1 : btl2) + n * 32 + k;
        valid = (n < PP && k >= 20);    // only pairs 352..363 contribute
        k += 332;                       // absolute pair index
    }
    float v = 0.f;
    if (valid) {
        int m = n - k - (mat == 0 ? 1 : 0);
        m %= PP; if (m < 0) m += PP;
        int d = 2 * m + 1;
        float t = (float)(3.14159265358979323846 * (double)d / (double)CC);
        float s = ((d >> 1) & 1) ? 1.f : -1.f;
        v = s * cosf(t) / ((float)CC * sinf(t));
    }
    *dst = (unsigned short)f2bf(v);
}

// Fused single-pass split GEMM:
//  A: raw fp32 x staged [128 r][64 ch] by pure global_load_lds DMA (XOR-chunk
//     swizzle via pre-swizzled source); fp32->bf16 cvt + even/odd de-interleave
//     on the READ side (overlaps MFMA). x is read ONCE from HBM.
//  B: [64 n][32 k] bf16 DMA tiles from L2-hot tables (tail tile uses btl*).
//  Schedule: R10's proven stage -> __syncthreads -> compute -> __syncthreads.
//   out[r][2n]   = relu(0.5 x[r][2n]   + sum_k Bt1[n][k] * x[r][2k+1])
//   out[r][2n+1] = relu(0.5 x[r][2n+1] + sum_k Bt2[n][k] * x[r][2k])
__global__ __launch_bounds__(256) void gemm_relu(
        const float* __restrict__ x,
        const unsigned short* __restrict__ bt1,
        const unsigned short* __restrict__ bt2,
        const unsigned short* __restrict__ btl1,
        const unsigned short* __restrict__ btl2,
        float* __restrict__ out) {
    __shared__ float ldsA[128 * 64];               // 32 KB fp32
    __shared__ unsigned short ldsB1[64 * 32];      // 4 KB
    __shared__ unsigned short ldsB2[64 * 32];      // 4 KB  => 40 KB total

    const int tid  = threadIdx.x;
    const int lane = tid & 63;
    const int wid  = tid >> 6;
    const int wr   = wid >> 1, wc = wid & 1;       // 2x2 wave grid
    const int l15  = lane & 15, lhi = lane >> 4;

    // bijective XCD swizzle (m204); 6 consecutive wgids share an x row-panel
    const int NX = 8;
    int orig = blockIdx.x;
    int q = NWG / NX, r = NWG % NX;                // 270, 6
    int xcd = orig % NX, local = orig / NX;
    int wgid = (xcd < r ? xcd * (q + 1) : r * (q + 1) + (xcd - r) * q) + local;
    const int bm  = (wgid / 6) * 128;
    const int bnp = (wgid % 6) * 64;               // pair-col base

    f32x4 acc_e[4][2], acc_o[4][2];
#pragma unroll
    for (int i = 0; i < 4; ++i)
#pragma unroll
        for (int j = 0; j < 2; ++j)
#pragma unroll
            for (int rr = 0; rr < 4; ++rr) { acc_e[i][j][rr] = 0.f; acc_o[i][j][rr] = 0.f; }

    const int brow = tid >> 2;     // 0..63: B staging row
    const int cq   = tid & 3;      // B 16B chunk id

#pragma unroll
    for (int kt = 0; kt < KT; ++kt) {
        const int cb = (kt < 11) ? kt * 64 : 664;  // channel base (always 64 valid)

        // ---- A: 8 DMA/thread, [row][chunk^(row&7)] source pre-swizzle ----
#pragma unroll
        for (int i = 0; i < 8; ++i) {
            int chunk = i * 256 + tid;             // 0..2047 (16B units)
            int row = chunk >> 4, c = chunk & 15;
            int cs  = c ^ (row & 7);               // inverse swizzle on source
            gload_lds16(x + (size_t)(bm + row) * CC + cb + cs * 4,
                        (char*)ldsA + (size_t)chunk * 16);
        }
        // ---- B: 2 DMA/thread, rotation-swizzled source (R10-proven) ----
        {
            int gsrc = (cq - (brow >> 1)) & 3;
            if (kt < 11) {
                size_t so = (size_t)(bnp + brow) * KP + kt * 32 + gsrc * 8;
                gload_lds16(bt1 + so, &ldsB1[tid * 8]);
                gload_lds16(bt2 + so, &ldsB2[tid * 8]);
            } else {
                size_t so = (size_t)(bnp + brow) * 32 + gsrc * 8;
                gload_lds16(btl1 + so, &ldsB1[tid * 8]);
                gload_lds16(btl2 + so, &ldsB2[tid * 8]);
            }
        }
        __syncthreads();   // drains DMA before reads

        // ---- A frags: ds_read fp32 + read-side cvt/de-interleave ----
        bf16x8 aE[4], aO[4], b1[2], b2[2];
#pragma unroll
        for (int mi = 0; mi < 4; ++mi) {
            int row = wr * 64 + mi * 16 + l15;
            union { bf16x8 v; unsigned int u[4]; } ue, uo;
#pragma unroll
            for (int j = 0; j < 4; ++j) {
                int c = (lhi * 4 + j) ^ (row & 7);
                float4 w = *(const float4*)&ldsA[row * 64 + c * 4];
                ue.u[j] = f2bf(w.x) | (f2bf(w.z) << 16);
                uo.u[j] = f2bf(w.y) | (f2bf(w.w) << 16);
            }
            aE[mi] = ue.v; aO[mi] = uo.v;
        }
#pragma unroll
        for (int nf = 0; nf < 2; ++nf) {
            int row = wc * 32 + nf * 16 + l15;
            int c   = (lhi + (row >> 1)) & 3;
            b1[nf] = *(const bf16x8*)&ldsB1[row * 32 + c * 8];
            b2[nf] = *(const bf16x8*)&ldsB2[row * 32 + c * 8];
        }
        __builtin_amdgcn_s_setprio(1);
#pragma unroll
        for (int mi = 0; mi < 4; ++mi)
#pragma unroll
            for (int nf = 0; nf < 2; ++nf) {
                acc_e[mi][nf] = __builtin_amdgcn_mfma_f32_16x16x32_bf16(
                    aO[mi], b1[nf], acc_e[mi][nf], 0, 0, 0);
                acc_o[mi][nf] = __builtin_amdgcn_mfma_f32_16x16x32_bf16(
                    aE[mi], b2[nf], acc_o[mi][nf], 0, 0, 0);
            }
        __builtin_amdgcn_s_setprio(0);
        __syncthreads();   // protect single-buffered LDS
    }

    // ---- epilogue: +0.5x identity (L3-hot fp32 re-read), relu, f2 store ----
#pragma unroll
    for (int mi = 0; mi < 4; ++mi) {
#pragma unroll
        for (int nf = 0; nf < 2; ++nf) {
            int colp = bnp + wc * 32 + nf * 16 + l15;
            if (colp < PP) {
#pragma unroll
                for (int rr = 0; rr < 4; ++rr) {
                    int rowg = bm + wr * 64 + mi * 16 + lhi * 4 + rr;
                    size_t base = (size_t)rowg * CC + 2 * colp;
                    float2 xv = *(const float2*)&x[base];
                    float2 ov;
                    float ye = 0.5f * xv.x + acc_e[mi][nf][rr];
                    float yo = 0.5f * xv.y + acc_o[mi][nf][rr];
                    ov.x = ye > 0.f ? ye : 0.f;
                    ov.y = yo > 0.f ? yo : 0.f;
                    *(float2*)&out[base] = ov;
                }
            }
        }
    }
}

extern "C" void kernel_launch(void* const* d_in, const int* in_sizes, int n_in,
                              void* d_out, int out_size, void* d_ws, size_t ws_size,
                              hipStream_t stream) {
    const float* x = (const float*)d_in[0];
    float* out = (float*)d_out;

    unsigned short* bt1  = (unsigned short*)d_ws;           // 384*384 bf16
    unsigned short* bt2  = bt1 + KP * KP;
    unsigned short* btl1 = bt2 + KP * KP;                   // 384*32 bf16
    unsigned short* btl2 = btl1 + KP * 32;

    int total = 2 * KP * KP + 2 * KP * 32;
    build_bt<<<(total + 255) / 256, 256, 0, stream>>>(bt1, bt2, btl1, btl2);
    gemm_relu<<<NWG, 256, 0, stream>>>(x, bt1, bt2, btl1, btl2, out);
}

// Round 19
// 114.776 us; speedup vs baseline: 2.6595x; 1.1394x over previous
//
#include <hip/hip_runtime.h>
#include <hip/hip_bf16.h>

#define CC 728
#define PP 364          // pairs (even/odd phase length)
#define KP 384          // padded pair-K: 6 * 64
#define KT 6            // K-steps of 64 pairs
#define M_ROWS 46208    // 32*38*38 = 361 * 128
#define NWG 2166        // 361 m-tiles * 6 n-tiles (64 pairs each)

typedef __attribute__((ext_vector_type(8))) short bf16x8;
typedef __attribute__((ext_vector_type(8))) unsigned short ushort8;
typedef __attribute__((ext_vector_type(4))) float f32x4;

// round-to-nearest-even fp32 -> bf16 bits
__device__ __forceinline__ unsigned int f2bf(float f) {
    unsigned int u = __float_as_uint(f);
    unsigned int r = u + 0x7fffu + ((u >> 16) & 1u);
    return r >> 16;
}

__device__ __forceinline__ float bf2f(unsigned short v) {
    unsigned int u = ((unsigned int)v) << 16;
    return __uint_as_float(u);
}

__device__ __forceinline__ void gload_lds16(const void* g, void* l) {
    __builtin_amdgcn_global_load_lds(
        (const __attribute__((address_space(1))) void*)g,
        (__attribute__((address_space(3))) void*)l,
        16, 0, 0);
}

// h[d] for odd d (validated closed form, rounds 1-18):
//   h[d] = s * cos(pi d/728) / (728 sin(pi d/728)),  s = +1 if (d>>1)&1 else -1
// Bt1[n][k] = h[2*((n-k-1) mod 364)+1]   (Ye = 0.5 E + Bt1 . O)
// Bt2[n][k] = h[2*((n-k)   mod 364)+1]   (Yo = 0.5 O + Bt2 . E)
// Both padded to [384][384] bf16, zero outside n<364 && k<364.
__global__ void build_bt(unsigned short* __restrict__ bt1,
                         unsigned short* __restrict__ bt2) {
    int idx = blockIdx.x * blockDim.x + threadIdx.x;
    if (idx >= 2 * KP * KP) return;
    int mat = idx / (KP * KP);
    int rem = idx % (KP * KP);
    int n = rem / KP, k = rem % KP;
    float v = 0.f;
    if (n < PP && k < PP) {
        int m = n - k - (mat == 0 ? 1 : 0);
        if (m < 0) m += PP;
        int d = 2 * m + 1;
        float t = (float)(3.14159265358979323846 * (double)d / (double)CC);
        float s = ((d >> 1) & 1) ? 1.f : -1.f;
        v = s * cosf(t) / ((float)CC * sinf(t));
    }
    (mat == 0 ? bt1 : bt2)[n * KP + k] = (unsigned short)f2bf(v);
}

// Pass 1: x fp32 [46208][728] -> e,o bf16 [46208][384] (de-interleaved, padded)
__global__ void convert_deint(const float* __restrict__ x,
                              unsigned short* __restrict__ e,
                              unsigned short* __restrict__ o) {
    int id = blockIdx.x * blockDim.x + threadIdx.x;   // r*48 + p8
    if (id >= M_ROWS * 48) return;
    int r  = id / 48, p8 = id % 48;
    int c0 = p8 * 16;
    ushort8 ve, vo;
#pragma unroll
    for (int j = 0; j < 8; ++j) { ve[j] = 0; vo[j] = 0; }
    if (c0 < CC) {
        const float4* src = (const float4*)(x + (size_t)r * CC + c0);
#pragma unroll
        for (int j = 0; j < 4; ++j) {
            float4 f = (c0 + 4 * j < CC) ? src[j] : make_float4(0.f, 0.f, 0.f, 0.f);
            ve[2 * j]     = (unsigned short)f2bf(f.x);
            vo[2 * j]     = (unsigned short)f2bf(f.y);
            ve[2 * j + 1] = (unsigned short)f2bf(f.z);
            vo[2 * j + 1] = (unsigned short)f2bf(f.w);
        }
    }
    *(ushort8*)(e + (size_t)r * KP + p8 * 8) = ve;
    *(ushort8*)(o + (size_t)r * KP + p8 * 8) = vo;
}

// Pass 2: split GEMM, R10's pure-DMA staging + 2-barrier schedule, BK=64:
// half the K-steps -> half the exposed per-step stage latencies. Subtiles
// processed sequentially inside a step to keep frag registers bounded.
//   out[r][2n]   = relu(0.5 E[r][n] + sum_k Bt1[n][k] * O[r][k])
//   out[r][2n+1] = relu(0.5 O[r][n] + sum_k Bt2[n][k] * E[r][k])
__global__ __launch_bounds__(256) void gemm_relu(
        const unsigned short* __restrict__ e,
        const unsigned short* __restrict__ o,
        const unsigned short* __restrict__ bt1,
        const unsigned short* __restrict__ bt2,
        float* __restrict__ out) {
    __shared__ unsigned short ldsE[128 * 64];    // 16 KB
    __shared__ unsigned short ldsO[128 * 64];    // 16 KB
    __shared__ unsigned short ldsB1[64 * 64];    // 8 KB
    __shared__ unsigned short ldsB2[64 * 64];    // 8 KB  => 48 KB

    const int tid  = threadIdx.x;
    const int lane = tid & 63;
    const int wid  = tid >> 6;
    const int wr   = wid >> 1, wc = wid & 1;     // 2x2 wave grid
    const int l15  = lane & 15, lhi = lane >> 4;

    // bijective XCD swizzle (m204); 6 consecutive wgids share an A row-panel.
    // m-panels consumed in REVERSE order: freshest convert output first (L3).
    const int NX = 8;
    int orig = blockIdx.x;
    int q = NWG / NX, r = NWG % NX;              // 270, 6
    int xcd = orig % NX, local = orig / NX;
    int wgid = (xcd < r ? xcd * (q + 1) : r * (q + 1) + (xcd - r) * q) + local;
    const int bm  = (360 - wgid / 6) * 128;
    const int bnp = (wgid % 6) * 64;             // pair-col base

    f32x4 acc_e[4][2], acc_o[4][2];
#pragma unroll
    for (int i = 0; i < 4; ++i)
#pragma unroll
        for (int j = 0; j < 2; ++j)
#pragma unroll
            for (int rr = 0; rr < 4; ++rr) { acc_e[i][j][rr] = 0.f; acc_o[i][j][rr] = 0.f; }

    // ---- staging: 12 DMA / thread / step; LDS [row][8 chunks], slot cq8
    // holds global chunk (cq8 - (row>>1)) & 7  (rotation swizzle, rule 21) ----
    auto stage = [&](int kt) {
        int k0 = kt * 64;
#pragma unroll
        for (int i = 0; i < 4; ++i) {            // E/O: 1024 chunks
            int c = i * 256 + tid;
            int row = c >> 3, cq8 = c & 7;
            int gsrc = (cq8 - (row >> 1)) & 7;
            size_t so = (size_t)(bm + row) * KP + k0 + gsrc * 8;
            gload_lds16(e + so, &ldsE[c * 8]);
            gload_lds16(o + so, &ldsO[c * 8]);
        }
#pragma unroll
        for (int i = 0; i < 2; ++i) {            // B: 512 chunks
            int c = i * 256 + tid;
            int row = c >> 3, cq8 = c & 7;
            int gsrc = (cq8 - (row >> 1)) & 7;
            size_t so = (size_t)(bnp + row) * KP + k0 + gsrc * 8;
            gload_lds16(bt1 + so, &ldsB1[c * 8]);
            gload_lds16(bt2 + so, &ldsB2[c * 8]);
        }
    };

    for (int kt = 0; kt < KT; ++kt) {
        stage(kt);
        __syncthreads();   // drains DMA before reads

        // two 32-pair subtiles sequentially (bounded frag registers)
#pragma unroll
        for (int kk = 0; kk < 2; ++kk) {
            bf16x8 aE[4], aO[4], b1[2], b2[2];
            const int g = kk * 4 + lhi;          // global chunk within step
#pragma unroll
            for (int mi = 0; mi < 4; ++mi) {
                int row  = wr * 64 + mi * 16 + l15;
                int slot = (g + (row >> 1)) & 7;
                aE[mi] = *(const bf16x8*)&ldsE[(row * 8 + slot) * 8];
                aO[mi] = *(const bf16x8*)&ldsO[(row * 8 + slot) * 8];
            }
#pragma unroll
            for (int nf = 0; nf < 2; ++nf) {
                int row  = wc * 32 + nf * 16 + l15;
                int slot = (g + (row >> 1)) & 7;
                b1[nf] = *(const bf16x8*)&ldsB1[(row * 8 + slot) * 8];
                b2[nf] = *(const bf16x8*)&ldsB2[(row * 8 + slot) * 8];
            }
            __builtin_amdgcn_s_setprio(1);
#pragma unroll
            for (int mi = 0; mi < 4; ++mi)
#pragma unroll
                for (int nf = 0; nf < 2; ++nf) {
                    acc_e[mi][nf] = __builtin_amdgcn_mfma_f32_16x16x32_bf16(
                        aO[mi], b1[nf], acc_e[mi][nf], 0, 0, 0);
                    acc_o[mi][nf] = __builtin_amdgcn_mfma_f32_16x16x32_bf16(
                        aE[mi], b2[nf], acc_o[mi][nf], 0, 0, 0);
                }
            __builtin_amdgcn_s_setprio(0);
        }
        __syncthreads();   // protect single-buffered LDS
    }

    // ---- epilogue: +0.5*E/O identity (L3-hot re-read), relu, float2 store ----
#pragma unroll
    for (int mi = 0; mi < 4; ++mi) {
#pragma unroll
        for (int nf = 0; nf < 2; ++nf) {
            int colp = bnp + wc * 32 + nf * 16 + l15;
            if (colp < PP) {
#pragma unroll
                for (int rr = 0; rr < 4; ++rr) {
                    int rowg = bm + wr * 64 + mi * 16 + lhi * 4 + rr;
                    size_t ib = (size_t)rowg * KP + colp;
                    float fe = bf2f(e[ib]);
                    float fo = bf2f(o[ib]);
                    float ye = 0.5f * fe + acc_e[mi][nf][rr];
                    float yo = 0.5f * fo + acc_o[mi][nf][rr];
                    float2 ov;
                    ov.x = ye > 0.f ? ye : 0.f;
                    ov.y = yo > 0.f ? yo : 0.f;
                    *(float2*)&out[(size_t)rowg * CC + 2 * colp] = ov;
                }
            }
        }
    }
}

extern "C" void kernel_launch(void* const* d_in, const int* in_sizes, int n_in,
                              void* d_out, int out_size, void* d_ws, size_t ws_size,
                              hipStream_t stream) {
    const float* x = (const float*)d_in[0];
    float* out = (float*)d_out;

    unsigned short* bt1 = (unsigned short*)d_ws;            // 384*384 bf16
    unsigned short* bt2 = bt1 + KP * KP;
    unsigned short* e   = bt2 + KP * KP;                    // 46208*384 bf16
    unsigned short* o   = e + (size_t)M_ROWS * KP;

    build_bt<<<(2 * KP * KP + 255) / 256, 256, 0, stream>>>(bt1, bt2);
    convert_deint<<<(M_ROWS * 48) / 256, 256, 0, stream>>>(x, e, o);
    gemm_relu<<<NWG, 256, 0, stream>>>(e, o, bt1, bt2, out);
}